// Round 6
// baseline (979.469 us; speedup 1.0000x reference)
//
#include <hip/hip_runtime.h>
#include <hip/hip_fp16.h>

// GCN 2-layer — ONE persistent mega-kernel (R6).
// R5 lesson: sum(dispatches) ~= 170us but total = 302us -> ~130us is
// inter-dispatch dead time (~8us/dispatch, confirmed by R1->R2 delta).
// So: collapse all 8 dispatches into one kernel with device-wide barriers.
//   phase A: edge histogram (256 vblocks) || weight transpose (96 vblocks)
//   phase B: per-bucket column scan of the block histograms
//   phase C: block-local scan of bucket totals + edge scatter into buckets
//   phase D: per-bucket fill: deg/rowptr/dinv + node-grouped srcIdx
//   phase E: y = half(x * dinv)   (all blocks, streaming)
//   phase F: fused gather + GEMM1(relu,b1) + GEMM2(*dinv) per 16-row tile
//            (dynamic claims of 2 tiles; guaranteed 8 blk/CU occupancy)
//   phase G: second-layer gather -> out  (dynamic claims of 16 nodes)
// Grid-wide sync: manual generation barrier. Arrival: agent-scope acq_rel
// fetch_add; spin: SYSTEM-scope relaxed poll (bypasses stale L1/L2 copies,
// no per-poll cache invalidate) + one agent acquire after release observed.
// Grid = blocksPerCU(query) * 256 CUs, capped 2048; launch_bounds(256,8)
// caps VGPR at 64 so query returns 8 -> all blocks co-resident.

constexpr int NN = 100000;   // nodes
constexpr int NE = 1600000;  // edges
constexpr int BSH = 7;       // 128 nodes per bucket
constexpr int NB = (NN + 127) >> BSH;  // 782 buckets
constexpr int NBLK = 256;    // binning virtual blocks
constexpr int EPB = NE / NBLK;  // 6250 edges per vblock (exact)
constexpr int TSTR = 784;    // table row stride (ints)
constexpr int NTILE = NN / 16;  // 6250 fused tiles (exact)
constexpr int NG4 = NN / 4;     // 25000 gath2 groups (exact)

typedef _Float16 f16x8 __attribute__((ext_vector_type(8)));
typedef float f32x4 __attribute__((ext_vector_type(4)));

// ---- device-wide barrier (all blocks resident by construction) ----
__device__ __forceinline__ void gsync(int* cnt, int* gen, int& local) {
  __syncthreads();
  if (threadIdx.x == 0) {
    int a = __hip_atomic_fetch_add(cnt, 1, __ATOMIC_ACQ_REL,
                                   __HIP_MEMORY_SCOPE_AGENT);
    if (a == (int)gridDim.x - 1) {
      __hip_atomic_store(cnt, 0, __ATOMIC_RELAXED, __HIP_MEMORY_SCOPE_AGENT);
      __hip_atomic_fetch_add(gen, 1, __ATOMIC_ACQ_REL,
                             __HIP_MEMORY_SCOPE_AGENT);
    } else {
      while (__hip_atomic_load(gen, __ATOMIC_RELAXED,
                               __HIP_MEMORY_SCOPE_SYSTEM) < local + 1)
        __builtin_amdgcn_s_sleep(2);
      (void)__hip_atomic_load(gen, __ATOMIC_ACQUIRE, __HIP_MEMORY_SCOPE_AGENT);
    }
  }
  local++;
  __syncthreads();
}

__global__ __launch_bounds__(256, 8) void k_mega(
    const float4* __restrict__ x4, const int* __restrict__ rows,
    const int* __restrict__ cols, const float* __restrict__ W1,
    const float* __restrict__ b1, const float* __restrict__ W2,
    const float* __restrict__ b2, float* __restrict__ out,
    int* __restrict__ table, int* __restrict__ startOff,
    int* __restrict__ btot, int* __restrict__ bucketBase,
    unsigned* __restrict__ binned, int* __restrict__ rowptr,
    int* __restrict__ deg, float* __restrict__ dinv,
    int* __restrict__ srcIdx, __half* __restrict__ Wt1,
    __half* __restrict__ Wt2, __half* __restrict__ y,
    __half* __restrict__ z, int* ctl) {
  __shared__ __align__(16) char smem[8704];
  __shared__ int sclaim;
  const int tid = threadIdx.x;
  const int nb_ = gridDim.x;
  int* bcnt = ctl + 0;
  int* bgen = ctl + 1;
  int local = 0;

  // ============ phase A: histogram (vb<NBLK) + weight transpose ============
  for (int vb = blockIdx.x; vb < NBLK + 96; vb += nb_) {
    if (vb < NBLK) {
      int* cnt = (int*)smem;  // NB ints
      for (int i = tid; i < NB; i += 256) cnt[i] = 0;
      __syncthreads();
      int base = vb * EPB;
      for (int i = tid; i < EPB; i += 256)
        atomicAdd(&cnt[cols[base + i] >> BSH], 1);
      __syncthreads();
      for (int i = tid; i < NB; i += 256) table[vb * TSTR + i] = cnt[i];
      __syncthreads();
    } else {
      int i = (vb - NBLK) * 256 + tid;  // 96*256 = 24576 = 16384 + 8192
      if (i < 16384) {
        int k = i >> 7, n = i & 127;
        Wt1[n * 128 + k] = __float2half(W1[i]);
      } else {
        int j = i - 16384;
        int k = j >> 6, n = j & 63;
        Wt2[n * 128 + k] = __float2half(W2[j]);
      }
    }
  }
  gsync(bcnt, bgen, local);

  // ============ phase B: scan table columns -> startOff, btot ============
  for (int vb = blockIdx.x; vb < NB; vb += nb_) {
    int* s = (int*)smem;
    int v = table[tid * TSTR + vb];
    s[tid] = v;
    __syncthreads();
    for (int off = 1; off < 256; off <<= 1) {
      int tmp = (tid >= off) ? s[tid - off] : 0;
      __syncthreads();
      s[tid] += tmp;
      __syncthreads();
    }
    startOff[tid * TSTR + vb] = s[tid] - v;
    if (tid == 255) btot[vb] = s[tid];
    __syncthreads();
  }
  gsync(bcnt, bgen, local);

  // ===== phase C: block-local scan of btot -> bb; scatter edges =====
  if (blockIdx.x < NBLK) {
    int* bb = (int*)smem;            // NB ints   (3128 B)
    int* s = (int*)(smem + 3200);    // 256 ints  (1024 B)
    int* scnt = (int*)(smem + 4352); // NB ints   (3128 B) -> 7480 total
    int base4 = tid * 4;
    int d0 = (base4 + 0 < NB) ? btot[base4 + 0] : 0;
    int d1 = (base4 + 1 < NB) ? btot[base4 + 1] : 0;
    int d2 = (base4 + 2 < NB) ? btot[base4 + 2] : 0;
    int d3 = (base4 + 3 < NB) ? btot[base4 + 3] : 0;
    int tsum = d0 + d1 + d2 + d3;
    s[tid] = tsum;
    __syncthreads();
    for (int off = 1; off < 256; off <<= 1) {
      int tmp = (tid >= off) ? s[tid - off] : 0;
      __syncthreads();
      s[tid] += tmp;
      __syncthreads();
    }
    int ex = s[tid] - tsum;
    if (base4 + 0 < NB) bb[base4 + 0] = ex;
    if (base4 + 1 < NB) bb[base4 + 1] = ex + d0;
    if (base4 + 2 < NB) bb[base4 + 2] = ex + d0 + d1;
    if (base4 + 3 < NB) bb[base4 + 3] = ex + d0 + d1 + d2;
    __syncthreads();
    if (blockIdx.x == 0)  // publish for phase D
      for (int i = tid; i < NB; i += 256) bucketBase[i] = bb[i];
    for (int vb = blockIdx.x; vb < NBLK; vb += nb_) {
      for (int i = tid; i < NB; i += 256)
        scnt[i] = bb[i] + startOff[vb * TSTR + i];
      __syncthreads();
      int base = vb * EPB;
      for (int i = tid; i < EPB; i += 256) {
        int c = cols[base + i];
        int r = rows[base + i];
        int pos = atomicAdd(&scnt[c >> BSH], 1);
        binned[pos] = ((unsigned)r << BSH) | (unsigned)(c & 127);
      }
      __syncthreads();
    }
  }
  gsync(bcnt, bgen, local);

  // ===== phase D: per-bucket fill: deg/rowptr/dinv + srcIdx =====
  for (int vb = blockIdx.x; vb < NB; vb += nb_) {
    int* cnt = (int*)smem;      // 128 ints
    int* sc = cnt + 128;        // 128 ints
    int* rp = sc + 128;         // 128 ints
    int nb0 = vb << BSH;
    int nn = min(128, NN - nb0);
    if (tid < 128) cnt[tid] = 0;
    __syncthreads();
    int ebeg = bucketBase[vb];
    int eend = ebeg + btot[vb];
    for (int p = ebeg + tid; p < eend; p += 256)
      atomicAdd(&cnt[binned[p] & 127], 1);
    __syncthreads();
    int v = (tid < 128) ? cnt[tid] : 0;
    if (tid < 128) sc[tid] = v;
    __syncthreads();
    for (int off = 1; off < 128; off <<= 1) {
      int tmp = (tid < 128 && tid >= off) ? sc[tid - off] : 0;
      __syncthreads();
      if (tid < 128) sc[tid] += tmp;
      __syncthreads();
    }
    if (tid < 128) {
      int ex = sc[tid] - v;
      rp[tid] = ebeg + ex;
      if (tid < nn) {
        rowptr[nb0 + tid] = ebeg + ex;
        deg[nb0 + tid] = v;
        dinv[nb0 + tid] = rsqrtf((float)v + 1.0f);
      }
      cnt[tid] = 0;
    }
    __syncthreads();
    for (int p = ebeg + tid; p < eend; p += 256) {
      unsigned pk = binned[p];
      int cl = pk & 127;
      int lo = atomicAdd(&cnt[cl], 1);
      srcIdx[rp[cl] + lo] = (int)(pk >> BSH);
    }
    __syncthreads();
  }
  gsync(bcnt, bgen, local);

  // ===== phase E: y = half(x * dinv), all blocks streaming =====
  {
    float2* y8 = (float2*)y;
    for (int i = blockIdx.x * 256 + tid; i < NN * 32; i += nb_ * 256) {
      float sfac = dinv[i >> 5];
      float4 vv = x4[i];
      union { __half2 h[2]; float2 f; } u;
      u.h[0] = __floats2half2_rn(vv.x * sfac, vv.y * sfac);
      u.h[1] = __floats2half2_rn(vv.z * sfac, vv.w * sfac);
      y8[i] = u.f;
    }
  }
  gsync(bcnt, bgen, local);

  // ===== phase F: fused gather + GEMM1 + GEMM2, dynamic 2-tile claims =====
  {
    __half(*sA)[136] = (__half(*)[136])smem;
    __half(*sB)[136] = (__half(*)[136])(smem + 4352);
    const int w = tid >> 6, l = tid & 63;
    const int quad = l >> 4, m = l & 15;
    for (;;) {
      if (tid == 0) sclaim = atomicAdd(ctl + 2, 1);
      __syncthreads();
      const int t0 = sclaim * 2;
      if (t0 >= NTILE) break;
      const int t1 = (t0 + 2 < NTILE) ? t0 + 2 : NTILE;
      for (int tile = t0; tile < t1; ++tile) {
        const int blk0 = tile * 16;
        // ---- gather: wave w -> rows [w*4, w*4+4), wave-uniform per node ----
        for (int i = 0; i < 4; ++i) {
          const int lr = w * 4 + i;
          const int node = blk0 + lr;
          const int d = deg[node];
          const int ptr = rowptr[node];
          float acc[8];
#pragma unroll
          for (int j = 0; j < 8; j++) acc[j] = 0.0f;
          for (int base = 0; base < d; base += 64) {
            int cntv = min(64, d - base);
            int my = (l < cntv) ? srcIdx[ptr + base + l] : 0;
            int k = 0;
            for (; k + 16 <= cntv; k += 16) {  // 4 loads (4KB) in flight
              int s0 = __shfl(my, k + quad);
              int s1 = __shfl(my, k + 4 + quad);
              int s2 = __shfl(my, k + 8 + quad);
              int s3 = __shfl(my, k + 12 + quad);
              f16x8 v0 = *(const f16x8*)(y + (size_t)s0 * 128 + m * 8);
              f16x8 v1 = *(const f16x8*)(y + (size_t)s1 * 128 + m * 8);
              f16x8 v2 = *(const f16x8*)(y + (size_t)s2 * 128 + m * 8);
              f16x8 v3 = *(const f16x8*)(y + (size_t)s3 * 128 + m * 8);
#pragma unroll
              for (int j = 0; j < 8; j++) acc[j] += (float)v0[j];
#pragma unroll
              for (int j = 0; j < 8; j++) acc[j] += (float)v1[j];
#pragma unroll
              for (int j = 0; j < 8; j++) acc[j] += (float)v2[j];
#pragma unroll
              for (int j = 0; j < 8; j++) acc[j] += (float)v3[j];
            }
            for (; k + 8 <= cntv; k += 8) {
              int s0 = __shfl(my, k + quad);
              int s1 = __shfl(my, k + 4 + quad);
              f16x8 v0 = *(const f16x8*)(y + (size_t)s0 * 128 + m * 8);
              f16x8 v1 = *(const f16x8*)(y + (size_t)s1 * 128 + m * 8);
#pragma unroll
              for (int j = 0; j < 8; j++) acc[j] += (float)v0[j];
#pragma unroll
              for (int j = 0; j < 8; j++) acc[j] += (float)v1[j];
            }
            for (; k < cntv; k += 4) {  // remainder, predicated
              int idx = k + quad;
              bool valid = idx < cntv;
              int s0 = __shfl(my, valid ? idx : 0);
              f16x8 v0 = *(const f16x8*)(y + (size_t)s0 * 128 + m * 8);
              if (valid) {
#pragma unroll
                for (int j = 0; j < 8; j++) acc[j] += (float)v0[j];
              }
            }
          }
#pragma unroll
          for (int j = 0; j < 8; j++) acc[j] += __shfl_xor(acc[j], 16);
#pragma unroll
          for (int j = 0; j < 8; j++) acc[j] += __shfl_xor(acc[j], 32);
          if (quad == 0) {
            f16x8 sv = *(const f16x8*)(y + (size_t)node * 128 + m * 8);
            float scn = dinv[node];
            f16x8 o;
#pragma unroll
            for (int j = 0; j < 8; j++)
              o[j] = (_Float16)((acc[j] + (float)sv[j]) * scn);
            *(f16x8*)(&sA[lr][m * 8]) = o;
          }
        }
        __syncthreads();
        // ---- GEMM1: h1 = relu(aggX @ W1 + b1); wave w -> cols 2w,2w+1 ----
        f16x8 afrag[4];
#pragma unroll
        for (int kk = 0; kk < 4; kk++)
          afrag[kk] = *(const f16x8*)(&sA[m][kk * 32 + quad * 8]);
        f32x4 acc1[2];
#pragma unroll
        for (int t = 0; t < 2; t++) {
          float bv = b1[(w * 2 + t) * 16 + m];
          acc1[t] = (f32x4){bv, bv, bv, bv};
        }
#pragma unroll
        for (int kk = 0; kk < 4; kk++) {
#pragma unroll
          for (int t = 0; t < 2; t++) {
            f16x8 b = *(const f16x8*)(Wt1 + (size_t)((w * 2 + t) * 16 + m) * 128 +
                                      kk * 32 + quad * 8);
            acc1[t] =
                __builtin_amdgcn_mfma_f32_16x16x32_f16(afrag[kk], b, acc1[t], 0, 0, 0);
          }
        }
#pragma unroll
        for (int t = 0; t < 2; t++)
#pragma unroll
          for (int i = 0; i < 4; i++)
            sB[quad * 4 + i][(w * 2 + t) * 16 + m] =
                __float2half(fmaxf(acc1[t][i], 0.0f));
        __syncthreads();
        // ---- GEMM2: z = (h1 @ W2) * dinv; wave w -> col tile w ----
        f16x8 hfrag[4];
#pragma unroll
        for (int kk = 0; kk < 4; kk++)
          hfrag[kk] = *(const f16x8*)(&sB[m][kk * 32 + quad * 8]);
        f32x4 acc2 = (f32x4){0.f, 0.f, 0.f, 0.f};
#pragma unroll
        for (int kk = 0; kk < 4; kk++) {
          f16x8 b = *(const f16x8*)(Wt2 + (size_t)(w * 16 + m) * 128 + kk * 32 +
                                    quad * 8);
          acc2 = __builtin_amdgcn_mfma_f32_16x16x32_f16(hfrag[kk], b, acc2, 0, 0, 0);
        }
        float rs[4];
#pragma unroll
        for (int i = 0; i < 4; i++) rs[i] = dinv[blk0 + quad * 4 + i];
#pragma unroll
        for (int i = 0; i < 4; i++)
          sA[quad * 4 + i][w * 16 + m] = __float2half(acc2[i] * rs[i]);
        __syncthreads();
        // ---- store 16x64 halves ----
        if (tid < 128) {
          int r = tid >> 3, cc = tid & 7;
          *(float4*)(z + (size_t)(blk0 + r) * 64 + cc * 8) =
              *(const float4*)(&sA[r][cc * 8]);
        }
        __syncthreads();  // protect sA/sclaim before next tile/claim
      }
    }
  }
  gsync(bcnt, bgen, local);

  // ===== phase G: second-layer gather -> out, dynamic 4-group claims =====
  {
    const int lane = tid & 63;
    const int g = lane >> 3;  // neighbor slot 0..7
    const int c = lane & 7;   // column chunk
    const size_t coff = (size_t)c * 8;
    for (;;) {
      if (tid == 0) sclaim = atomicAdd(ctl + 3, 1);
      __syncthreads();
      const int g0 = sclaim * 4;
      if (g0 >= NG4) break;
      const int g1 = (g0 + 4 < NG4) ? g0 + 4 : NG4;
      for (int gg = g0; gg < g1; ++gg) {
        int node = gg * 4 + (tid >> 6);
        int d = deg[node];
        int p = rowptr[node];
        float acc[8];
#pragma unroll
        for (int i = 0; i < 8; i++) acc[i] = 0.0f;
        for (int base = 0; base < d; base += 64) {
          int cnt = min(64, d - base);
          int my = (lane < cnt) ? srcIdx[p + base + lane] : 0;
          int k = 0;
          for (; k + 16 <= cnt; k += 16) {
            int s0 = __shfl(my, k + g);
            int s1 = __shfl(my, k + 8 + g);
            f16x8 v0 = *(const f16x8*)(z + (size_t)s0 * 64 + coff);
            f16x8 v1 = *(const f16x8*)(z + (size_t)s1 * 64 + coff);
#pragma unroll
            for (int i = 0; i < 8; i++) acc[i] += (float)v0[i];
#pragma unroll
            for (int i = 0; i < 8; i++) acc[i] += (float)v1[i];
          }
          for (; k < cnt; k += 8) {
            int idx = k + g;
            bool valid = idx < cnt;
            int s0 = __shfl(my, valid ? idx : 0);
            f16x8 v0 = *(const f16x8*)(z + (size_t)s0 * 64 + coff);
            if (valid) {
#pragma unroll
              for (int i = 0; i < 8; i++) acc[i] += (float)v0[i];
            }
          }
        }
#pragma unroll
        for (int i = 0; i < 8; i++) acc[i] += __shfl_xor(acc[i], 8);
#pragma unroll
        for (int i = 0; i < 8; i++) acc[i] += __shfl_xor(acc[i], 16);
#pragma unroll
        for (int i = 0; i < 8; i++) acc[i] += __shfl_xor(acc[i], 32);
        if (g == 0) {
          f16x8 sv = *(const f16x8*)(z + (size_t)node * 64 + coff);
          float s = dinv[node];
          const float4* b4 = (const float4*)b2;
          float4 bv0 = b4[2 * c], bv1 = b4[2 * c + 1];
          float4 o0, o1;
          o0.x = (acc[0] + (float)sv[0]) * s + bv0.x;
          o0.y = (acc[1] + (float)sv[1]) * s + bv0.y;
          o0.z = (acc[2] + (float)sv[2]) * s + bv0.z;
          o0.w = (acc[3] + (float)sv[3]) * s + bv0.w;
          o1.x = (acc[4] + (float)sv[4]) * s + bv1.x;
          o1.y = (acc[5] + (float)sv[5]) * s + bv1.y;
          o1.z = (acc[6] + (float)sv[6]) * s + bv1.z;
          o1.w = (acc[7] + (float)sv[7]) * s + bv1.w;
          float4* op = (float4*)(out + (size_t)node * 64 + coff);
          op[0] = o0;
          op[1] = o1;
        }
      }
      __syncthreads();  // protect sclaim
    }
  }
}

extern "C" void kernel_launch(void* const* d_in, const int* in_sizes, int n_in,
                              void* d_out, int out_size, void* d_ws, size_t ws_size,
                              hipStream_t stream) {
  const float* x = (const float*)d_in[0];
  const int* ei = (const int*)d_in[1];  // [2, NE] (int32: JAX x64 disabled)
  const int* rows = ei;
  const int* cols = ei + NE;
  const float* W1 = (const float*)d_in[3];
  const float* b1 = (const float*)d_in[4];
  const float* W2 = (const float*)d_in[5];
  const float* b2 = (const float*)d_in[6];
  float* out = (float*)d_out;

  // ---- workspace carve (~60 MB) ----
  char* base = (char*)d_ws;
  constexpr size_t MB = 1 << 20;
  int* deg = (int*)(base + 0 * MB);
  int* rowptr = (int*)(base + 1 * MB);
  float* dinv = (float*)(base + 2 * MB);
  int* btot = (int*)(base + 3 * MB);                    // 3.2 KB
  int* bucketBase = (int*)(base + 3 * MB + 16 * 1024);  // 3.2 KB
  __half* Wt1 = (__half*)(base + 3 * MB + 64 * 1024);   // 32 KB
  __half* Wt2 = (__half*)(base + 3 * MB + 128 * 1024);  // 16 KB
  int* ctl = (int*)(base + 3 * MB + 512 * 1024);        // 16 B control block
  int* table = (int*)(base + 4 * MB);                   // 803 KB
  int* startOff = (int*)(base + 5 * MB);                // 803 KB
  unsigned* binned = (unsigned*)(base + 6 * MB);        // 6.4 MB
  int* srcIdx = (int*)(base + 13 * MB);                 // 6.4 MB
  __half* y = (__half*)(base + 20 * MB);                // 25.6 MB
  __half* z = (__half*)(base + 46 * MB);                // 12.8 MB

  // zero the barrier/claim counters (captured into the graph, runs per replay)
  hipMemsetAsync(ctl, 0, 16, stream);

  static int nblk = 0;
  if (nblk == 0) {
    int b = 0;
    if (hipOccupancyMaxActiveBlocksPerMultiprocessor(&b, k_mega, 256, 0) !=
            hipSuccess ||
        b < 1)
      b = 4;            // conservative fallback, still co-resident
    if (b > 8) b = 8;   // 8 blk/CU is the 256-thread cap
    nblk = b * 256;     // 256 CUs on MI355X
  }

  k_mega<<<nblk, 256, 0, stream>>>(
      (const float4*)x, rows, cols, W1, b1, W2, b2, out, table, startOff, btot,
      bucketBase, binned, rowptr, deg, dinv, srcIdx, Wt1, Wt2, y, z, ctl);
}